// Round 9
// baseline (431.593 us; speedup 1.0000x reference)
//
#include <hip/hip_runtime.h>

#define F_IN 128
#define F_HID 16
#define N_CLS 10
#define TILE 16384          // edges per level-1 tile
#define SH_C 10             // coarse bucket = dst >> 10 (1024 nodes)
#define RB 128              // fine bucket = 128 nodes
#define CAP 12800           // max edges per fine bucket (mean ~8.2k, sigma ~90)

// bf16 helpers
__device__ __forceinline__ unsigned bpack2(float a, float b) {
    unsigned ua = __float_as_uint(a), ub = __float_as_uint(b);
    ua = (ua + 0x7fffu + ((ua >> 16) & 1u)) >> 16;
    ub = (ub + 0x7fffu + ((ub >> 16) & 1u)) >> 16;
    return ua | (ub << 16);
}
__device__ __forceinline__ float blo(unsigned w) { return __uint_as_float(w << 16); }
__device__ __forceinline__ float bhi(unsigned w) { return __uint_as_float(w & 0xffff0000u); }

// ====== hist: per-tile coarse histogram + per-quartile fine totals ======

__global__ __launch_bounds__(256) void k_hist2(const int* __restrict__ dst,
                                               int* __restrict__ th,      // [nt][nbc]
                                               int* __restrict__ qtot,    // [nfb*4] pre-zeroed
                                               int ne, int nt, int nbc, int nfb) {
    __shared__ int h[1024];
    int t = blockIdx.x;
    for (int i = threadIdx.x; i < nfb; i += 256) h[i] = 0;
    __syncthreads();
    int e0 = t * TILE, e1 = min(e0 + TILE, ne);
    for (int i = e0 + threadIdx.x; i < e1; i += 256)
        atomicAdd(&h[dst[i] >> 7], 1);
    __syncthreads();
    if (threadIdx.x < nbc) {
        int s = 0;
#pragma unroll
        for (int f = 0; f < 8; ++f) s += h[threadIdx.x * 8 + f];
        th[t * nbc + threadIdx.x] = s;
    }
    int q = (t * 4) / nt;   // monotone in t
    for (int i = threadIdx.x; i < nfb; i += 256)
        if (h[i]) atomicAdd(&qtot[i * 4 + q], h[i]);
}

// ====== per-coarse-bucket scan across tiles ======

__global__ __launch_bounds__(256) void k_colscan(int* __restrict__ th, int nt, int nbc) {
    int b = blockIdx.x;
    __shared__ int sm[256];
    __shared__ int s_run;
    if (threadIdx.x == 0) s_run = 0;
    __syncthreads();
    for (int t0 = 0; t0 < nt; t0 += 256) {
        int t = t0 + threadIdx.x;
        int v = (t < nt) ? th[t * nbc + b] : 0;
        sm[threadIdx.x] = v;
        __syncthreads();
        int acc = v;
        for (int d = 1; d < 256; d <<= 1) {
            int add = (threadIdx.x >= d) ? sm[threadIdx.x - d] : 0;
            __syncthreads();
            acc += add;
            sm[threadIdx.x] = acc;
            __syncthreads();
        }
        int run = s_run;
        if (t < nt) th[t * nbc + b] = run + acc - v;
        __syncthreads();
        if (threadIdx.x == 255) s_run = run + acc;
        __syncthreads();
    }
}

// ====== chunked exclusive scan of qtot[nb] -> qbases[0..nb] ======

__global__ __launch_bounds__(1024) void k_bscan(const int* __restrict__ tot,
                                                int* __restrict__ bases, int nb) {
    __shared__ int sm[1024];
    __shared__ int s_run;
    if (threadIdx.x == 0) s_run = 0;
    __syncthreads();
    for (int base = 0; base < nb; base += 1024) {
        int i = base + threadIdx.x;
        int v = (i < nb) ? tot[i] : 0;
        sm[threadIdx.x] = v;
        __syncthreads();
        int acc = v;
        for (int d = 1; d < 1024; d <<= 1) {
            int add = (threadIdx.x >= d) ? sm[threadIdx.x - d] : 0;
            __syncthreads();
            acc += add;
            sm[threadIdx.x] = acc;
            __syncthreads();
        }
        int run = s_run;
        if (i < nb) bases[i] = run + acc - v;
        __syncthreads();
        if (threadIdx.x == 1023) s_run = run + acc;
        __syncthreads();
    }
    if (threadIdx.x == 0) bases[nb] = s_run;
}

// ====== level-1 scatter into coarse-bucket-grouped array ======
// pack = (dst_low10 << 20) | src

__global__ __launch_bounds__(256) void k_tilescatter(const int* __restrict__ src,
                                                     const int* __restrict__ dst,
                                                     const int* __restrict__ th,
                                                     const int* __restrict__ qbases,
                                                     int* __restrict__ csr, int ne, int nbc) {
    __shared__ int cur[128];
    int t = blockIdx.x;
    for (int i = threadIdx.x; i < nbc; i += 256)
        cur[i] = qbases[i * 32] + th[t * nbc + i];
    __syncthreads();
    int e0 = t * TILE, e1 = min(e0 + TILE, ne);
    for (int i = e0 + threadIdx.x; i < e1; i += 256) {
        int d = dst[i], s = src[i];
        int b = d >> SH_C;
        int p = atomicAdd(&cur[b], 1);
        csr[p] = ((d & 1023) << 20) | s;
    }
}

// ====== level-2 split: (coarse, quartile) -> 8 fine buckets ======

__global__ __launch_bounds__(1024) void k_split(const int* __restrict__ csr,
                                                const int* __restrict__ qtot,
                                                const int* __restrict__ qbases,
                                                int* __restrict__ csr2) {
    __shared__ int cur8[8];
    __shared__ int s_rs, s_re;
    int cb = blockIdx.x >> 2, qq = blockIdx.x & 3;
    if (threadIdx.x < 8) cur8[threadIdx.x] = qbases[(cb * 8 + threadIdx.x) * 4 + qq];
    if (threadIdx.x == 0) {
        int S = qbases[cb * 32];
        int off = 0;
        for (int q = 0; q < qq; ++q)
#pragma unroll
            for (int f = 0; f < 8; ++f) off += qtot[(cb * 8 + f) * 4 + q];
        int c = 0;
#pragma unroll
        for (int f = 0; f < 8; ++f) c += qtot[(cb * 8 + f) * 4 + qq];
        s_rs = S + off;
        s_re = S + off + c;
    }
    __syncthreads();
    int rs = s_rs, re = s_re;
    for (int i = rs + (int)threadIdx.x; i < re; i += 1024) {
        int p = csr[i];
        int fid = (p >> 27) & 7;
        int pos = atomicAdd(&cur8[fid], 1);
        csr2[pos] = p;
    }
}

// ====== per-fine-bucket node sort (single global read) + dinv + offs ======

__global__ __launch_bounds__(256) void k_bsort(int* __restrict__ csr2,
                                               const int* __restrict__ qbases,
                                               float* __restrict__ dinv,
                                               int* __restrict__ offs,
                                               int n, int ne) {
    __shared__ int ebuf[CAP];   // 51.2 KB
    __shared__ int h[RB];
    __shared__ int sc[RB];
    __shared__ int cur[RB];
    int fb = blockIdx.x;
    int e0 = qbases[fb * 4], e1 = qbases[fb * 4 + 4];
    int cnt = e1 - e0;
    if (threadIdx.x < RB) h[threadIdx.x] = 0;
    __syncthreads();
    for (int i = e0 + threadIdx.x; i < e1; i += 256) {
        int p = csr2[i];
        ebuf[i - e0] = p;
        atomicAdd(&h[(p >> 20) & 127], 1);
    }
    __syncthreads();
    if (threadIdx.x < RB) sc[threadIdx.x] = h[threadIdx.x];
    __syncthreads();
    for (int d = 1; d < RB; d <<= 1) {
        int v = 0;
        if (threadIdx.x < RB && threadIdx.x >= d) v = sc[threadIdx.x - d];
        __syncthreads();
        if (threadIdx.x < RB) sc[threadIdx.x] += v;
        __syncthreads();
    }
    if (threadIdx.x < RB) {
        int excl = sc[threadIdx.x] - h[threadIdx.x];
        cur[threadIdx.x] = excl;
        int node = (fb << 7) + threadIdx.x;
        if (node < n) {
            dinv[node] = rsqrtf((float)(h[threadIdx.x] + 1));  // +1 self-loop
            offs[node] = e0 + excl;
        }
    }
    if (fb == 0 && threadIdx.x == 0) offs[n] = ne;
    __syncthreads();
    // scatter LDS -> global (writes land in this bucket's ~32-50KB window, L2-absorbed)
    for (int j = threadIdx.x; j < cnt; j += 256) {
        int p = ebuf[j];
        int pos = atomicAdd(&cur[(p >> 20) & 127], 1);
        csr2[e0 + pos] = p & 0xFFFFF;
    }
}

// ====== layer 1 linear (pre-scaled, bf16 out) ======

__global__ __launch_bounds__(256) void k_gemm1(const float* __restrict__ x,
                                               const float* __restrict__ W1,
                                               const float* __restrict__ dinv,
                                               unsigned* __restrict__ h1s, int n) {
    __shared__ float Ws[F_IN * F_HID];
    __shared__ float xs[16][F_IN + 1];
    __shared__ float ys[16][17];
    for (int i = threadIdx.x; i < F_IN * F_HID; i += 256) Ws[i] = W1[i];
    int node0 = blockIdx.x * 16;
    for (int i = threadIdx.x; i < 16 * F_IN; i += 256) {
        int r = i >> 7, c = i & 127;
        int node = node0 + r;
        xs[r][c] = (node < n) ? x[(size_t)node * F_IN + c] : 0.f;
    }
    __syncthreads();
    int r = threadIdx.x >> 4, f = threadIdx.x & 15;
    int node = node0 + r;
    float acc = 0.f;
    if (node < n) {
#pragma unroll
        for (int k = 0; k < F_IN; ++k) acc = fmaf(xs[r][k], Ws[k * F_HID + f], acc);
        acc *= dinv[node];
    }
    ys[r][f] = acc;
    __syncthreads();
    if (threadIdx.x < 128) {
        int rr = threadIdx.x >> 3, w = threadIdx.x & 7;
        int nd = node0 + rr;
        if (nd < n)
            h1s[(size_t)nd * 8 + w] = bpack2(ys[rr][2 * w], ys[rr][2 * w + 1]);
    }
}

// ====== aggregation layer 1: wave/node, 16 slots x 4 chunks, 4-deep ======

__global__ __launch_bounds__(256) void k_agg1(const int* __restrict__ csr,
                                              const int* __restrict__ offs,
                                              const float* __restrict__ dinv,
                                              const unsigned* __restrict__ h1s,
                                              const float* __restrict__ b1,
                                              unsigned* __restrict__ h1s2, int n) {
    int node = blockIdx.x * 4 + (threadIdx.x >> 6);
    if (node >= n) return;
    int lane = threadIdx.x & 63;
    int e = lane & 15, c = lane >> 4;
    int off = offs[node], end = offs[node + 1];
    const uint2* h2 = (const uint2*)h1s;
    float a0 = 0.f, a1 = 0.f, a2 = 0.f, a3 = 0.f;
    int i = off + e;
    for (; i + 48 < end; i += 64) {
        int s0 = csr[i], s1 = csr[i + 16], s2 = csr[i + 32], s3 = csr[i + 48];
        uint2 v0 = h2[(size_t)s0 * 4 + c];
        uint2 v1 = h2[(size_t)s1 * 4 + c];
        uint2 v2 = h2[(size_t)s2 * 4 + c];
        uint2 v3 = h2[(size_t)s3 * 4 + c];
        a0 += (blo(v0.x) + blo(v1.x)) + (blo(v2.x) + blo(v3.x));
        a1 += (bhi(v0.x) + bhi(v1.x)) + (bhi(v2.x) + bhi(v3.x));
        a2 += (blo(v0.y) + blo(v1.y)) + (blo(v2.y) + blo(v3.y));
        a3 += (bhi(v0.y) + bhi(v1.y)) + (bhi(v2.y) + bhi(v3.y));
    }
    for (; i < end; i += 16) {
        uint2 v = h2[(size_t)csr[i] * 4 + c];
        a0 += blo(v.x); a1 += bhi(v.x); a2 += blo(v.y); a3 += bhi(v.y);
    }
#pragma unroll
    for (int m = 1; m <= 8; m <<= 1) {
        a0 += __shfl_xor(a0, m); a1 += __shfl_xor(a1, m);
        a2 += __shfl_xor(a2, m); a3 += __shfl_xor(a3, m);
    }
    if (e == 0) {
        float dd = dinv[node];
        uint2 sv = h2[(size_t)node * 4 + c];
        float v0 = (a0 + blo(sv.x)) * dd + b1[c * 4 + 0];
        float v1 = (a1 + bhi(sv.x)) * dd + b1[c * 4 + 1];
        float v2 = (a2 + blo(sv.y)) * dd + b1[c * 4 + 2];
        float v3 = (a3 + bhi(sv.y)) * dd + b1[c * 4 + 3];
        v0 = fmaxf(v0, 0.f) * dd; v1 = fmaxf(v1, 0.f) * dd;
        v2 = fmaxf(v2, 0.f) * dd; v3 = fmaxf(v3, 0.f) * dd;
        uint2 o; o.x = bpack2(v0, v1); o.y = bpack2(v2, v3);
        ((uint2*)h1s2)[(size_t)node * 4 + c] = o;
    }
}

// ====== aggregation layer 2: 4-deep loop + LDS two-phase epilogue ======
// NOTE: no early return (barriers); n = 100000 is divisible by 4.

__global__ __launch_bounds__(256) void k_agg2(const int* __restrict__ csr,
                                              const int* __restrict__ offs,
                                              const float* __restrict__ dinv,
                                              const unsigned* __restrict__ h1s2,
                                              const float* __restrict__ W2,
                                              const float* __restrict__ b2,
                                              float* __restrict__ out, int n) {
    __shared__ float gs[4][16];     // per-wave g vectors
    __shared__ float lo_s[4][10];   // logits
    int w = threadIdx.x >> 6;
    int node = blockIdx.x * 4 + w;
    int lane = threadIdx.x & 63;
    int e = lane & 15, c = lane >> 4;
    bool act = node < n;
    const uint2* h2 = (const uint2*)h1s2;
    float a0 = 0.f, a1 = 0.f, a2 = 0.f, a3 = 0.f;
    if (act) {
        int off = offs[node], end = offs[node + 1];
        int i = off + e;
        for (; i + 48 < end; i += 64) {
            int s0 = csr[i], s1 = csr[i + 16], s2 = csr[i + 32], s3 = csr[i + 48];
            uint2 v0 = h2[(size_t)s0 * 4 + c];
            uint2 v1 = h2[(size_t)s1 * 4 + c];
            uint2 v2 = h2[(size_t)s2 * 4 + c];
            uint2 v3 = h2[(size_t)s3 * 4 + c];
            a0 += (blo(v0.x) + blo(v1.x)) + (blo(v2.x) + blo(v3.x));
            a1 += (bhi(v0.x) + bhi(v1.x)) + (bhi(v2.x) + bhi(v3.x));
            a2 += (blo(v0.y) + blo(v1.y)) + (blo(v2.y) + blo(v3.y));
            a3 += (bhi(v0.y) + bhi(v1.y)) + (bhi(v2.y) + bhi(v3.y));
        }
        for (; i < end; i += 16) {
            uint2 v = h2[(size_t)csr[i] * 4 + c];
            a0 += blo(v.x); a1 += bhi(v.x); a2 += blo(v.y); a3 += bhi(v.y);
        }
#pragma unroll
        for (int m = 1; m <= 8; m <<= 1) {
            a0 += __shfl_xor(a0, m); a1 += __shfl_xor(a1, m);
            a2 += __shfl_xor(a2, m); a3 += __shfl_xor(a3, m);
        }
        if (e == 0) {
            float dd = dinv[node];
            uint2 sv = h2[(size_t)node * 4 + c];
            float g0 = (a0 + blo(sv.x)) * dd;
            float g1 = (a1 + bhi(sv.x)) * dd;
            float g2 = (a2 + blo(sv.y)) * dd;
            float g3 = (a3 + bhi(sv.y)) * dd;
            gs[w][c * 4 + 0] = g0; gs[w][c * 4 + 1] = g1;
            gs[w][c * 4 + 2] = g2; gs[w][c * 4 + 3] = g3;
        }
    }
    __syncthreads();
    int t = threadIdx.x;
    float lg = 0.f;
    int nd = t / 10, cl = t - nd * 10;
    if (t < 40 && blockIdx.x * 4 + nd < n) {
        lg = b2[cl];
#pragma unroll
        for (int k = 0; k < F_HID; ++k)
            lg = fmaf(gs[nd][k], W2[k * N_CLS + cl], lg);
        lo_s[nd][cl] = lg;
    }
    __syncthreads();
    if (t < 40 && blockIdx.x * 4 + nd < n) {
        float v0 = lo_s[nd][0], v1 = lo_s[nd][1], v2 = lo_s[nd][2], v3 = lo_s[nd][3];
        float v4 = lo_s[nd][4], v5 = lo_s[nd][5], v6 = lo_s[nd][6], v7 = lo_s[nd][7];
        float v8 = lo_s[nd][8], v9 = lo_s[nd][9];
        float m = fmaxf(fmaxf(fmaxf(v0, v1), fmaxf(v2, v3)),
                        fmaxf(fmaxf(fmaxf(v4, v5), fmaxf(v6, v7)), fmaxf(v8, v9)));
        float s = __expf(v0 - m) + __expf(v1 - m) + __expf(v2 - m) + __expf(v3 - m) +
                  __expf(v4 - m) + __expf(v5 - m) + __expf(v6 - m) + __expf(v7 - m) +
                  __expf(v8 - m) + __expf(v9 - m);
        float lse = m + __logf(s);
        out[(size_t)(blockIdx.x * 4 + nd) * N_CLS + cl] = lg - lse;
    }
}

extern "C" void kernel_launch(void* const* d_in, const int* in_sizes, int n_in,
                              void* d_out, int out_size, void* d_ws, size_t ws_size,
                              hipStream_t stream) {
    const float* x  = (const float*)d_in[0];
    const int*   ei = (const int*)d_in[1];
    const float* W1 = (const float*)d_in[2];
    const float* b1 = (const float*)d_in[3];
    const float* W2 = (const float*)d_in[4];
    const float* b2 = (const float*)d_in[5];
    float* out = (float*)d_out;

    const int n  = in_sizes[0] / F_IN;   // 100000
    const int ne = in_sizes[1] / 2;      // 6400000
    const int* src = ei;
    const int* dst = ei + ne;

    const int nbc = (n + (1 << SH_C) - 1) >> SH_C;   // 98 coarse
    const int nfb = nbc * 8;                          // 784 fine
    const int nq  = nfb * 4;                          // 3136 (fine, quartile)
    const int nt  = (ne + TILE - 1) / TILE;           // 391 tiles

    char* ws = (char*)d_ws;
    size_t off = 0;
    auto carve = [&](size_t bytes) -> void* {
        void* p = ws + off;
        off += (bytes + 255) & ~(size_t)255;
        return p;
    };
    int*      th     = (int*)     carve((size_t)nt * nbc * 4);
    int*      qtot   = (int*)     carve((size_t)nq * 4);
    int*      qbases = (int*)     carve((size_t)(nq + 1) * 4);
    float*    dinv   = (float*)   carve((size_t)n * 4);
    int*      csr    = (int*)     carve((size_t)ne * 4);       // 25.6 MB
    int*      csr2   = (int*)     carve((size_t)ne * 4);       // 25.6 MB
    int*      offsA  = (int*)     carve((size_t)(n + 1) * 4);
    unsigned* h1s    = (unsigned*)carve((size_t)n * 8 * 4);    // 3.2 MB
    unsigned* h1s2   = (unsigned*)carve((size_t)n * 8 * 4);    // 3.2 MB
    (void)ws_size;

    hipMemsetAsync(qtot, 0, (size_t)nq * 4, stream);

    k_hist2<<<nt, 256, 0, stream>>>(dst, th, qtot, ne, nt, nbc, nfb);
    k_colscan<<<nbc, 256, 0, stream>>>(th, nt, nbc);
    k_bscan<<<1, 1024, 0, stream>>>(qtot, qbases, nq);
    k_tilescatter<<<nt, 256, 0, stream>>>(src, dst, th, qbases, csr, ne, nbc);
    k_split<<<nbc * 4, 1024, 0, stream>>>(csr, qtot, qbases, csr2);
    k_bsort<<<nfb, 256, 0, stream>>>(csr2, qbases, dinv, offsA, n, ne);

    k_gemm1<<<(n + 15) / 16, 256, 0, stream>>>(x, W1, dinv, h1s, n);
    k_agg1<<<(n + 3) / 4, 256, 0, stream>>>(csr2, offsA, dinv, h1s, b1, h1s2, n);
    k_agg2<<<(n + 3) / 4, 256, 0, stream>>>(csr2, offsA, dinv, h1s2, W2, b2, out, n);
}

// Round 10
// 424.192 us; speedup vs baseline: 1.0174x; 1.0174x over previous
//
#include <hip/hip_runtime.h>

#define F_IN 128
#define F_HID 16
#define N_CLS 10
#define TILE 16384          // edges per level-1 tile
#define SH_C 10             // coarse bucket = dst >> 10 (1024 nodes)
#define RB 128              // fine bucket = 128 nodes
#define CAP 12800           // max edges per fine bucket (mean ~8.2k, sigma ~90)
#define EBUF 768            // agg LDS edge-stage cap (4 nodes, mean 256, sigma 16)

// bf16 helpers
__device__ __forceinline__ unsigned bpack2(float a, float b) {
    unsigned ua = __float_as_uint(a), ub = __float_as_uint(b);
    ua = (ua + 0x7fffu + ((ua >> 16) & 1u)) >> 16;
    ub = (ub + 0x7fffu + ((ub >> 16) & 1u)) >> 16;
    return ua | (ub << 16);
}
__device__ __forceinline__ float blo(unsigned w) { return __uint_as_float(w << 16); }
__device__ __forceinline__ float bhi(unsigned w) { return __uint_as_float(w & 0xffff0000u); }

// ====== hist: per-tile coarse histogram + global fine totals ======

__global__ __launch_bounds__(256) void k_hist2(const int* __restrict__ dst,
                                               int* __restrict__ th,      // [nt][nbc]
                                               int* __restrict__ ftot,    // [nfb] pre-zeroed
                                               int ne, int nbc, int nfb) {
    __shared__ int h[1024];
    int t = blockIdx.x;
    for (int i = threadIdx.x; i < nfb; i += 256) h[i] = 0;
    __syncthreads();
    int e0 = t * TILE, e1 = min(e0 + TILE, ne);
    for (int i = e0 + threadIdx.x; i < e1; i += 256)
        atomicAdd(&h[dst[i] >> 7], 1);
    __syncthreads();
    if (threadIdx.x < nbc) {
        int s = 0;
#pragma unroll
        for (int f = 0; f < 8; ++f) s += h[threadIdx.x * 8 + f];
        th[t * nbc + threadIdx.x] = s;
    }
    for (int i = threadIdx.x; i < nfb; i += 256)
        if (h[i]) atomicAdd(&ftot[i], h[i]);
}

// ====== per-coarse-bucket scan across tiles ======

__global__ __launch_bounds__(256) void k_colscan(int* __restrict__ th, int nt, int nbc) {
    int b = blockIdx.x;
    __shared__ int sm[256];
    __shared__ int s_run;
    if (threadIdx.x == 0) s_run = 0;
    __syncthreads();
    for (int t0 = 0; t0 < nt; t0 += 256) {
        int t = t0 + threadIdx.x;
        int v = (t < nt) ? th[t * nbc + b] : 0;
        sm[threadIdx.x] = v;
        __syncthreads();
        int acc = v;
        for (int d = 1; d < 256; d <<= 1) {
            int add = (threadIdx.x >= d) ? sm[threadIdx.x - d] : 0;
            __syncthreads();
            acc += add;
            sm[threadIdx.x] = acc;
            __syncthreads();
        }
        int run = s_run;
        if (t < nt) th[t * nbc + b] = run + acc - v;
        __syncthreads();
        if (threadIdx.x == 255) s_run = run + acc;
        __syncthreads();
    }
}

// ====== exclusive scan of fine totals -> fbases[0..nfb] ======

__global__ __launch_bounds__(1024) void k_bscan(const int* __restrict__ totals,
                                                int* __restrict__ bases, int nb) {
    __shared__ int sm[1024];
    int t = threadIdx.x;
    int v = (t < nb) ? totals[t] : 0;
    sm[t] = v;
    __syncthreads();
    int acc = v;
    for (int d = 1; d < 1024; d <<= 1) {
        int add = (t >= d) ? sm[t - d] : 0;
        __syncthreads();
        acc += add;
        sm[t] = acc;
        __syncthreads();
    }
    if (t < nb) bases[t] = acc - v;
    if (t == nb - 1) bases[nb] = acc;
}

// ====== level-1 scatter into coarse-bucket-grouped array ======
// pack = (dst_low10 << 20) | src

__global__ __launch_bounds__(256) void k_tilescatter(const int* __restrict__ src,
                                                     const int* __restrict__ dst,
                                                     const int* __restrict__ th,
                                                     const int* __restrict__ fbases,
                                                     int* __restrict__ csr, int ne, int nbc) {
    __shared__ int cur[128];
    int t = blockIdx.x;
    for (int i = threadIdx.x; i < nbc; i += 256)
        cur[i] = fbases[i * 8] + th[t * nbc + i];
    __syncthreads();
    int e0 = t * TILE, e1 = min(e0 + TILE, ne);
    for (int i = e0 + threadIdx.x; i < e1; i += 256) {
        int d = dst[i], s = src[i];
        int b = d >> SH_C;
        int p = atomicAdd(&cur[b], 1);
        csr[p] = ((d & 1023) << 20) | s;
    }
}

// ====== level-2 split: coarse bucket -> 8 fine buckets ======

__global__ __launch_bounds__(1024) void k_split(const int* __restrict__ csr,
                                                const int* __restrict__ fbases,
                                                int* __restrict__ csr2, int nbc) {
    __shared__ int cur8[8];
    int bu = blockIdx.x;
    if (threadIdx.x < 8) cur8[threadIdx.x] = fbases[bu * 8 + threadIdx.x];
    __syncthreads();
    int e0 = fbases[bu * 8], e1 = fbases[bu * 8 + 8];
    for (int i = e0 + (int)threadIdx.x; i < e1; i += 1024) {
        int p = csr[i];
        int fid = (p >> 27) & 7;
        int pos = atomicAdd(&cur8[fid], 1);
        csr2[pos] = p;
    }
}

// ====== per-fine-bucket node sort (in place) + dinv + offs ======

__global__ __launch_bounds__(256) void k_bsort(int* __restrict__ csr,
                                               const int* __restrict__ fbases,
                                               float* __restrict__ dinv,
                                               int* __restrict__ offs,
                                               int n, int ne) {
    __shared__ int s_src[CAP];
    __shared__ int h[RB];
    __shared__ int sc[RB];
    __shared__ int cur[RB];
    int bu = blockIdx.x;
    int e0 = fbases[bu], e1 = fbases[bu + 1];
    int cnt = e1 - e0;
    if (threadIdx.x < RB) h[threadIdx.x] = 0;
    __syncthreads();
    for (int i = e0 + threadIdx.x; i < e1; i += 256)
        atomicAdd(&h[(csr[i] >> 20) & 127], 1);
    __syncthreads();
    if (threadIdx.x < RB) sc[threadIdx.x] = h[threadIdx.x];
    __syncthreads();
    for (int d = 1; d < RB; d <<= 1) {
        int v = 0;
        if (threadIdx.x < RB && threadIdx.x >= d) v = sc[threadIdx.x - d];
        __syncthreads();
        if (threadIdx.x < RB) sc[threadIdx.x] += v;
        __syncthreads();
    }
    if (threadIdx.x < RB) {
        int excl = sc[threadIdx.x] - h[threadIdx.x];
        cur[threadIdx.x] = excl;
        int node = (bu << 7) + threadIdx.x;
        if (node < n) {
            dinv[node] = rsqrtf((float)(h[threadIdx.x] + 1));  // +1 self-loop
            offs[node] = e0 + excl;
        }
    }
    if (bu == 0 && threadIdx.x == 0) offs[n] = ne;
    __syncthreads();
    for (int i = e0 + threadIdx.x; i < e1; i += 256) {
        int p = csr[i];
        int pos = atomicAdd(&cur[(p >> 20) & 127], 1);
        s_src[pos] = p & 0xFFFFF;
    }
    __syncthreads();
    for (int j = threadIdx.x; j < cnt; j += 256)
        csr[e0 + j] = s_src[j];
}

// ====== layer 1 linear (pre-scaled, bf16 out) ======

__global__ __launch_bounds__(256) void k_gemm1(const float* __restrict__ x,
                                               const float* __restrict__ W1,
                                               const float* __restrict__ dinv,
                                               unsigned* __restrict__ h1s, int n) {
    __shared__ float Ws[F_IN * F_HID];
    __shared__ float xs[16][F_IN + 1];
    __shared__ float ys[16][17];
    for (int i = threadIdx.x; i < F_IN * F_HID; i += 256) Ws[i] = W1[i];
    int node0 = blockIdx.x * 16;
    for (int i = threadIdx.x; i < 16 * F_IN; i += 256) {
        int r = i >> 7, c = i & 127;
        int node = node0 + r;
        xs[r][c] = (node < n) ? x[(size_t)node * F_IN + c] : 0.f;
    }
    __syncthreads();
    int r = threadIdx.x >> 4, f = threadIdx.x & 15;
    int node = node0 + r;
    float acc = 0.f;
    if (node < n) {
#pragma unroll
        for (int k = 0; k < F_IN; ++k) acc = fmaf(xs[r][k], Ws[k * F_HID + f], acc);
        acc *= dinv[node];
    }
    ys[r][f] = acc;
    __syncthreads();
    if (threadIdx.x < 128) {
        int rr = threadIdx.x >> 3, w = threadIdx.x & 7;
        int nd = node0 + rr;
        if (nd < n)
            h1s[(size_t)nd * 8 + w] = bpack2(ys[rr][2 * w], ys[rr][2 * w + 1]);
    }
}

// gather body over an int* edge list (LDS or global)
#define GATHER_LOOP(EL)                                                        \
    for (; i + 48 < oe; i += 64) {                                             \
        int s0 = EL[i], s1 = EL[i + 16], s2 = EL[i + 32], s3 = EL[i + 48];     \
        uint2 v0 = h2[(size_t)s0 * 4 + c];                                     \
        uint2 v1 = h2[(size_t)s1 * 4 + c];                                     \
        uint2 v2 = h2[(size_t)s2 * 4 + c];                                     \
        uint2 v3 = h2[(size_t)s3 * 4 + c];                                     \
        a0 += (blo(v0.x) + blo(v1.x)) + (blo(v2.x) + blo(v3.x));               \
        a1 += (bhi(v0.x) + bhi(v1.x)) + (bhi(v2.x) + bhi(v3.x));               \
        a2 += (blo(v0.y) + blo(v1.y)) + (blo(v2.y) + blo(v3.y));               \
        a3 += (bhi(v0.y) + bhi(v1.y)) + (bhi(v2.y) + bhi(v3.y));               \
    }                                                                          \
    for (; i < oe; i += 16) {                                                  \
        uint2 v = h2[(size_t)EL[i] * 4 + c];                                   \
        a0 += blo(v.x); a1 += bhi(v.x); a2 += blo(v.y); a3 += bhi(v.y);        \
    }

// ====== aggregation layer 1: LDS-staged csr, wave/node, 16 slots x 4 chunks ======

__global__ __launch_bounds__(256) void k_agg1(const int* __restrict__ csr,
                                              const int* __restrict__ offs,
                                              const float* __restrict__ dinv,
                                              const unsigned* __restrict__ h1s,
                                              const float* __restrict__ b1,
                                              unsigned* __restrict__ h1s2, int n) {
    __shared__ int ebuf[EBUF];
    int node0 = blockIdx.x * 4;
    int w = threadIdx.x >> 6;
    int node = node0 + w;
    int estart = offs[node0];
    int eend = offs[min(node0 + 4, n)];
    int cnt = eend - estart;
    bool fits = (cnt <= EBUF);
    if (fits) {
        for (int j = threadIdx.x; j < cnt; j += 256) ebuf[j] = csr[estart + j];
    }
    __syncthreads();
    if (node >= n) return;
    int lane = threadIdx.x & 63;
    int e = lane & 15, c = lane >> 4;
    const uint2* h2 = (const uint2*)h1s;
    float a0 = 0.f, a1 = 0.f, a2 = 0.f, a3 = 0.f;
    int o = offs[node] - estart, oe = offs[node + 1] - estart;
    int i = o + e;
    if (fits) {
        GATHER_LOOP(ebuf)
    } else {
        const int* gl = csr + estart;
        GATHER_LOOP(gl)
    }
#pragma unroll
    for (int m = 1; m <= 8; m <<= 1) {
        a0 += __shfl_xor(a0, m); a1 += __shfl_xor(a1, m);
        a2 += __shfl_xor(a2, m); a3 += __shfl_xor(a3, m);
    }
    if (e == 0) {
        float dd = dinv[node];
        uint2 sv = h2[(size_t)node * 4 + c];
        float v0 = (a0 + blo(sv.x)) * dd + b1[c * 4 + 0];
        float v1 = (a1 + bhi(sv.x)) * dd + b1[c * 4 + 1];
        float v2 = (a2 + blo(sv.y)) * dd + b1[c * 4 + 2];
        float v3 = (a3 + bhi(sv.y)) * dd + b1[c * 4 + 3];
        v0 = fmaxf(v0, 0.f) * dd; v1 = fmaxf(v1, 0.f) * dd;
        v2 = fmaxf(v2, 0.f) * dd; v3 = fmaxf(v3, 0.f) * dd;
        uint2 o2; o2.x = bpack2(v0, v1); o2.y = bpack2(v2, v3);
        ((uint2*)h1s2)[(size_t)node * 4 + c] = o2;
    }
}

// ====== aggregation layer 2: LDS-staged csr + LDS two-phase epilogue ======

__global__ __launch_bounds__(256) void k_agg2(const int* __restrict__ csr,
                                              const int* __restrict__ offs,
                                              const float* __restrict__ dinv,
                                              const unsigned* __restrict__ h1s2,
                                              const float* __restrict__ W2,
                                              const float* __restrict__ b2,
                                              float* __restrict__ out, int n) {
    __shared__ int ebuf[EBUF];
    __shared__ float gs[4][16];
    __shared__ float lo_s[4][10];
    int node0 = blockIdx.x * 4;
    int w = threadIdx.x >> 6;
    int node = node0 + w;
    int estart = offs[node0];
    int eend = offs[min(node0 + 4, n)];
    int cnt = eend - estart;
    bool fits = (cnt <= EBUF);
    if (fits) {
        for (int j = threadIdx.x; j < cnt; j += 256) ebuf[j] = csr[estart + j];
    }
    __syncthreads();
    int lane = threadIdx.x & 63;
    int e = lane & 15, c = lane >> 4;
    bool act = node < n;
    const uint2* h2 = (const uint2*)h1s2;
    if (act) {
        float a0 = 0.f, a1 = 0.f, a2 = 0.f, a3 = 0.f;
        int o = offs[node] - estart, oe = offs[node + 1] - estart;
        int i = o + e;
        if (fits) {
            GATHER_LOOP(ebuf)
        } else {
            const int* gl = csr + estart;
            GATHER_LOOP(gl)
        }
#pragma unroll
        for (int m = 1; m <= 8; m <<= 1) {
            a0 += __shfl_xor(a0, m); a1 += __shfl_xor(a1, m);
            a2 += __shfl_xor(a2, m); a3 += __shfl_xor(a3, m);
        }
        if (e == 0) {
            float dd = dinv[node];
            uint2 sv = h2[(size_t)node * 4 + c];
            gs[w][c * 4 + 0] = (a0 + blo(sv.x)) * dd;
            gs[w][c * 4 + 1] = (a1 + bhi(sv.x)) * dd;
            gs[w][c * 4 + 2] = (a2 + blo(sv.y)) * dd;
            gs[w][c * 4 + 3] = (a3 + bhi(sv.y)) * dd;
        }
    }
    __syncthreads();
    int t = threadIdx.x;
    int nd = t / 10, cl = t - nd * 10;
    float lg = 0.f;
    if (t < 40 && node0 + nd < n) {
        lg = b2[cl];
#pragma unroll
        for (int k = 0; k < F_HID; ++k)
            lg = fmaf(gs[nd][k], W2[k * N_CLS + cl], lg);
        lo_s[nd][cl] = lg;
    }
    __syncthreads();
    if (t < 40 && node0 + nd < n) {
        float v0 = lo_s[nd][0], v1 = lo_s[nd][1], v2 = lo_s[nd][2], v3 = lo_s[nd][3];
        float v4 = lo_s[nd][4], v5 = lo_s[nd][5], v6 = lo_s[nd][6], v7 = lo_s[nd][7];
        float v8 = lo_s[nd][8], v9 = lo_s[nd][9];
        float m = fmaxf(fmaxf(fmaxf(v0, v1), fmaxf(v2, v3)),
                        fmaxf(fmaxf(fmaxf(v4, v5), fmaxf(v6, v7)), fmaxf(v8, v9)));
        float s = __expf(v0 - m) + __expf(v1 - m) + __expf(v2 - m) + __expf(v3 - m) +
                  __expf(v4 - m) + __expf(v5 - m) + __expf(v6 - m) + __expf(v7 - m) +
                  __expf(v8 - m) + __expf(v9 - m);
        float lse = m + __logf(s);
        out[(size_t)(node0 + nd) * N_CLS + cl] = lg - lse;
    }
}

extern "C" void kernel_launch(void* const* d_in, const int* in_sizes, int n_in,
                              void* d_out, int out_size, void* d_ws, size_t ws_size,
                              hipStream_t stream) {
    const float* x  = (const float*)d_in[0];
    const int*   ei = (const int*)d_in[1];
    const float* W1 = (const float*)d_in[2];
    const float* b1 = (const float*)d_in[3];
    const float* W2 = (const float*)d_in[4];
    const float* b2 = (const float*)d_in[5];
    float* out = (float*)d_out;

    const int n  = in_sizes[0] / F_IN;   // 100000
    const int ne = in_sizes[1] / 2;      // 6400000
    const int* src = ei;
    const int* dst = ei + ne;

    const int nbc = (n + (1 << SH_C) - 1) >> SH_C;   // 98
    const int nfb = nbc * 8;                          // 784
    const int nt  = (ne + TILE - 1) / TILE;           // 391

    char* ws = (char*)d_ws;
    size_t off = 0;
    auto carve = [&](size_t bytes) -> void* {
        void* p = ws + off;
        off += (bytes + 255) & ~(size_t)255;
        return p;
    };
    int*      th     = (int*)     carve((size_t)nt * nbc * 4);
    int*      ftot   = (int*)     carve((size_t)nfb * 4);
    int*      fbases = (int*)     carve((size_t)(nfb + 1) * 4);
    float*    dinv   = (float*)   carve((size_t)n * 4);
    int*      csr    = (int*)     carve((size_t)ne * 4);       // 25.6 MB
    int*      csr2   = (int*)     carve((size_t)ne * 4);       // 25.6 MB
    int*      offsA  = (int*)     carve((size_t)(n + 1) * 4);
    unsigned* h1s    = (unsigned*)carve((size_t)n * 8 * 4);    // 3.2 MB
    unsigned* h1s2   = (unsigned*)carve((size_t)n * 8 * 4);    // 3.2 MB
    (void)ws_size;

    hipMemsetAsync(ftot, 0, (size_t)nfb * 4, stream);

    k_hist2<<<nt, 256, 0, stream>>>(dst, th, ftot, ne, nbc, nfb);
    k_colscan<<<nbc, 256, 0, stream>>>(th, nt, nbc);
    k_bscan<<<1, 1024, 0, stream>>>(ftot, fbases, nfb);
    k_tilescatter<<<nt, 256, 0, stream>>>(src, dst, th, fbases, csr, ne, nbc);
    k_split<<<nbc, 1024, 0, stream>>>(csr, fbases, csr2, nbc);
    k_bsort<<<nfb, 256, 0, stream>>>(csr2, fbases, dinv, offsA, n, ne);

    k_gemm1<<<(n + 15) / 16, 256, 0, stream>>>(x, W1, dinv, h1s, n);
    k_agg1<<<(n + 3) / 4, 256, 0, stream>>>(csr2, offsA, dinv, h1s, b1, h1s2, n);
    k_agg2<<<(n + 3) / 4, 256, 0, stream>>>(csr2, offsA, dinv, h1s2, W2, b2, out, n);
}